// Round 11
// baseline (99.037 us; speedup 1.0000x reference)
//
#include <hip/hip_runtime.h>
#include <hip/hip_bf16.h>

#define NN 8192
#define DD 256
#define LOG2E 1.4426950408889634f
#define LN2f 0.6931471805599453f

typedef unsigned int uint32;
typedef __attribute__((ext_vector_type(4))) int i32x4;
typedef __attribute__((ext_vector_type(8))) int i32x8;
typedef __attribute__((ext_vector_type(4))) float f32x4;

__device__ __forceinline__ float epsf(float w) {
    return 1.f - 0.9f / (1.f + __expf(-5.f * w));
}

// One wave per row: L2-normalize, fold (logit_scale*log2e) into f1 side, emit
// OCP fp8-e4m3 rows (packed 4/lane) + exact fp32 diag, zero rse/cse, and
// accumulate analytic S/T vectors into 64-way partial buffers. [r8-verified]
__global__ __launch_bounds__(256) void nrm_kernel(
    const float* __restrict__ f1, const float* __restrict__ f2,
    const float* __restrict__ scale_p, const float* __restrict__ wts,
    uint32* __restrict__ f1q, uint32* __restrict__ f2q,
    float* __restrict__ diag, float* __restrict__ rse, float* __restrict__ cse,
    float* __restrict__ S1p, float* __restrict__ S2p,
    float* __restrict__ T1p, float* __restrict__ T2p)
{
    __shared__ float4 red[4][256];
    const int w = threadIdx.x >> 6, lane = threadIdx.x & 63;
    const int row = blockIdx.x * 4 + w;
    const float4 a = reinterpret_cast<const float4*>(f1 + (size_t)row * DD)[lane];
    const float4 b = reinterpret_cast<const float4*>(f2 + (size_t)row * DD)[lane];
    float sa = a.x * a.x + a.y * a.y + a.z * a.z + a.w * a.w;
    float sb = b.x * b.x + b.y * b.y + b.z * b.z + b.w * b.w;
    float sab = a.x * b.x + a.y * b.y + a.z * b.z + a.w * b.w;
#pragma unroll
    for (int off = 1; off < 64; off <<= 1) {
        sa += __shfl_xor(sa, off);
        sb += __shfl_xor(sb, off);
        sab += __shfl_xor(sab, off);
    }
    const float s = scale_p[0];
    const float n1 = fmaxf(sqrtf(sa), 1e-12f);
    const float n2 = fmaxf(sqrtf(sb), 1e-12f);
    const float e = epsf(wts[row]);
    if (lane == 0) { diag[row] = s * sab / (n1 * n2); rse[row] = 0.f; cse[row] = 0.f; }
    const float r1 = s * LOG2E / n1, r2 = 1.0f / n2;
    const float v0 = a.x * r1, v1 = a.y * r1, v2 = a.z * r1, v3 = a.w * r1;
    const float u0 = b.x * r2, u1 = b.y * r2, u2 = b.z * r2, u3 = b.w * r2;
    uint32 q1 = __builtin_amdgcn_cvt_pk_fp8_f32(v0, v1, 0, false);
    q1 = __builtin_amdgcn_cvt_pk_fp8_f32(v2, v3, q1, true);
    uint32 q2 = __builtin_amdgcn_cvt_pk_fp8_f32(u0, u1, 0, false);
    q2 = __builtin_amdgcn_cvt_pk_fp8_f32(u2, u3, q2, true);
    f1q[(size_t)row * 64 + lane] = q1;
    f2q[(size_t)row * 64 + lane] = q2;
    red[w][lane * 4 + 0] = make_float4(v0, e * v0, u0, e * u0);
    red[w][lane * 4 + 1] = make_float4(v1, e * v1, u1, e * u1);
    red[w][lane * 4 + 2] = make_float4(v2, e * v2, u2, e * u2);
    red[w][lane * 4 + 3] = make_float4(v3, e * v3, u3, e * u3);
    __syncthreads();
    const int c = threadIdx.x;
    const int part = (blockIdx.x & 63) * 256 + c;
    const float4 q0 = red[0][c], qq1 = red[1][c], qq2 = red[2][c], qq3 = red[3][c];
    atomicAdd(&S1p[part], q0.x + qq1.x + qq2.x + qq3.x);
    atomicAdd(&T1p[part], q0.y + qq1.y + qq2.y + qq3.y);
    atomicAdd(&S2p[part], q0.z + qq1.z + qq2.z + qq3.z);
    atomicAdd(&T2p[part], q0.w + qq1.w + qq2.w + qq3.w);
}

// MX-FP8 GEMM [r8-verified numerics]: block = 128 rows x 512 cols, 1024
// blocks. A (full K=256, fp8) in 64 regs/wave; B-tiles of 64 cols (16 KB)
// double-buffered in LDS via global_load_lds with 4-bit XOR chunk swizzle
// (both sides, rule #21). K=256 = 2 k-steps of mfma_scale 16x16x128
// (scales=1.0). Only change vs r8: launch_bounds (256,3)->(256,2) -- the
// 84-VGPR cap was the spill trigger (r8: 100MB FETCH / 185MB WRITE scratch).
__global__ __launch_bounds__(256, 2) void gemm_kernel(
    const uint32* __restrict__ f1q, const uint32* __restrict__ f2q,
    float* __restrict__ rowsumexp, float* __restrict__ colsumexp)
{
    __shared__ char Bs[2][64 * 256];     // 2 x 16 KB
    __shared__ float colbuf[2][512];     // 4 KB
    const int bid = blockIdx.x;
    const int bm = bid >> 4, bc = bid & 15;
    const int w = threadIdx.x >> 6, lane = threadIdx.x & 63;
    const int wr = (w >> 1) * 64, wc = (w & 1) * 32;   // wave: 64 rows x 32 cols
    const int lhi = lane >> 4, llo = lane & 15;

    // A frags: av[m][ks] = f1q[bm*128+wr+m*16+llo][bytes ks*128 + lhi*32 .. +32)
    const char* aBase = (const char*)f1q + (size_t)(bm * 128 + wr + llo) * 256 + lhi * 32;
    i32x8 av[4][2];
#pragma unroll
    for (int m = 0; m < 4; ++m)
#pragma unroll
        for (int ks = 0; ks < 2; ++ks)
            av[m][ks] = *(const i32x8*)(aBase + (size_t)(m * 16) * 256 + ks * 128);
#pragma unroll
    for (int m = 0; m < 4; ++m)
#pragma unroll
        for (int ks = 0; ks < 2; ++ks)
            asm volatile("" : "+v"(av[m][ks]));   // pin: forbid remat

    const char* bBase = (const char*)f2q + (size_t)(bc * 512) * 256;

    auto stage = [&](int buf, int tile) {
        const char* src = bBase + (size_t)(tile * 64) * 256;
#pragma unroll
        for (int i = 0; i < 4; ++i) {
            const int id = w * 256 + i * 64 + lane;          // chunk slot 0..1023
            const int r = id >> 4;                            // source row (col of B)
            const int cs = (id & 15) ^ (r & 15);              // pre-swizzled chunk
            __builtin_amdgcn_global_load_lds(
                (const __attribute__((address_space(1))) unsigned int*)(src + (size_t)r * 256 + cs * 16),
                (__attribute__((address_space(3))) unsigned int*)(&Bs[buf][(w * 256 + i * 64) * 16]),
                16, 0, 0);
        }
    };

    float rowpart[16];
#pragma unroll
    for (int i = 0; i < 16; ++i) rowpart[i] = 0.f;

    const uint32 SC1 = 0x7f7f7f7fu;   // e8m0 = 127 -> scale 1.0 for all blocks

    stage(0, 0);
    __syncthreads();

    for (int t = 0; t < 8; ++t) {
        const int cur = t & 1;
        if (t < 7) stage(cur ^ 1, t + 1);   // issue next-tile loads BEFORE compute

        const char* bs = Bs[cur];
        f32x4 acc[4][2];
#pragma unroll
        for (int m = 0; m < 4; ++m) {
            acc[m][0] = (f32x4){0.f, 0.f, 0.f, 0.f};
            acc[m][1] = (f32x4){0.f, 0.f, 0.f, 0.f};
        }
#pragma unroll
        for (int ks = 0; ks < 2; ++ks) {
            const int kb = ks * 8 + lhi * 2;                 // base k-chunk (16B units)
#pragma unroll
            for (int n = 0; n < 2; ++n) {
                const int col = wc + n * 16 + llo;
                const i32x4 blo = *(const i32x4*)(bs + col * 256 + ((kb + 0) ^ llo) * 16);
                const i32x4 bhi = *(const i32x4*)(bs + col * 256 + ((kb + 1) ^ llo) * 16);
                const i32x8 bv = {blo[0], blo[1], blo[2], blo[3],
                                  bhi[0], bhi[1], bhi[2], bhi[3]};
#pragma unroll
                for (int m = 0; m < 4; ++m)
                    acc[m][n] = __builtin_amdgcn_mfma_scale_f32_16x16x128_f8f6f4(
                        av[m][ks], bv, acc[m][n], 0, 0, 0, SC1, 0, SC1);
            }
        }

        // epilogue: exp2 (log2e folded into A) + row/col accumulation
        float cee0 = 0.f, cee1 = 0.f;
#pragma unroll
        for (int m = 0; m < 4; ++m)
#pragma unroll
            for (int j = 0; j < 4; ++j) {
                const float e0 = __builtin_exp2f(acc[m][0][j]);
                const float e1 = __builtin_exp2f(acc[m][1][j]);
                rowpart[m * 4 + j] += e0 + e1;
                cee0 += e0; cee1 += e1;
            }
        cee0 += __shfl_xor(cee0, 16); cee0 += __shfl_xor(cee0, 32);
        cee1 += __shfl_xor(cee1, 16); cee1 += __shfl_xor(cee1, 32);
        if (lhi == 0) {
            colbuf[w >> 1][t * 64 + wc + llo] = cee0;
            colbuf[w >> 1][t * 64 + wc + 16 + llo] = cee1;
        }
        __syncthreads();
    }

    // block-end: row expsums (row = wr + m*16 + lhi*4 + j; reduce over llo)
#pragma unroll
    for (int m = 0; m < 4; ++m)
#pragma unroll
        for (int j = 0; j < 4; ++j) {
            float v = rowpart[m * 4 + j];
            v += __shfl_xor(v, 1); v += __shfl_xor(v, 2);
            v += __shfl_xor(v, 4); v += __shfl_xor(v, 8);
            if (llo == 0)
                atomicAdd(&rowsumexp[bm * 128 + wr + m * 16 + lhi * 4 + j], v);
        }
    // col expsums: combine the two row-half partials
    for (int c = threadIdx.x; c < 512; c += 256)
        atomicAdd(&colsumexp[bc * 512 + c], colbuf[0][c] + colbuf[1][c]);
}

// Single block, 1024 threads: per-row loss terms + parallel S/T partial
// reduction + analytic dot correction (x LN2 for the log2e scaling of f1).
// [r6-verified]
__global__ __launch_bounds__(1024) void fin_kernel(
    const float* __restrict__ rse, const float* __restrict__ cse,
    const float* __restrict__ diag, const float* __restrict__ wts,
    const float* __restrict__ S1p, const float* __restrict__ S2p,
    const float* __restrict__ T1p, const float* __restrict__ T2p,
    float* __restrict__ out)
{
    const int t = threadIdx.x;
    float a = 0.f;
#pragma unroll
    for (int k = 0; k < 8; ++k) {
        const int i = t + k * 1024;
        a += __logf(rse[i]) + __logf(cse[i]) - 2.f * (1.f - epsf(wts[i])) * diag[i];
    }
    __shared__ float4 pr4[4][256];
    {
        const int col = t & 255, seg = t >> 8;
        float s1 = 0.f, t1 = 0.f, s2 = 0.f, t2 = 0.f;
#pragma unroll
        for (int q = 0; q < 16; ++q) {
            const int idx = (seg * 16 + q) * 256 + col;
            s1 += S1p[idx]; t1 += T1p[idx]; s2 += S2p[idx]; t2 += T2p[idx];
        }
        pr4[seg][col] = make_float4(s1, t1, s2, t2);
    }
    __syncthreads();
    if (t < 256) {
        const float4 q0 = pr4[0][t], q1 = pr4[1][t], q2 = pr4[2][t], q3 = pr4[3][t];
        const float s1 = q0.x + q1.x + q2.x + q3.x;
        const float t1 = q0.y + q1.y + q2.y + q3.y;
        const float s2 = q0.z + q1.z + q2.z + q3.z;
        const float t2 = q0.w + q1.w + q2.w + q3.w;
        a -= (t1 * s2 + s1 * t2) * (LN2f / (float)NN);
    }
#pragma unroll
    for (int off = 1; off < 64; off <<= 1) a += __shfl_xor(a, off);
    __shared__ float red[16];
    if ((t & 63) == 0) red[t >> 6] = a;
    __syncthreads();
    if (t == 0) {
        float tot = 0.f;
#pragma unroll
        for (int i = 0; i < 16; ++i) tot += red[i];
        out[0] = tot * (1.f / (2.f * (float)NN));
    }
}

extern "C" void kernel_launch(void* const* d_in, const int* in_sizes, int n_in,
                              void* d_out, int out_size, void* d_ws, size_t ws_size,
                              hipStream_t stream) {
    (void)in_sizes; (void)n_in; (void)out_size; (void)ws_size;
    const float* f1 = (const float*)d_in[0];
    const float* f2 = (const float*)d_in[1];
    const float* scale = (const float*)d_in[2];
    const float* wts = (const float*)d_in[3];
    float* out = (float*)d_out;

    char* ws = (char*)d_ws;
    uint32* f1q = (uint32*)ws;                                   // 2 MB fp8
    uint32* f2q = (uint32*)(ws + (size_t)2 * 1024 * 1024);       // 2 MB fp8
    float* fb = (float*)(ws + (size_t)4 * 1024 * 1024);
    float* rse  = fb;                  // 8192
    float* cse  = fb + 8192;           // 8192
    float* diag = fb + 16384;          // 8192
    float* S1p  = fb + 24576;          // 64*256 each
    float* S2p  = fb + 24576 + 16384;
    float* T1p  = fb + 24576 + 32768;
    float* T2p  = fb + 24576 + 49152;

    hipMemsetAsync(S1p, 0, (size_t)4 * 16384 * sizeof(float), stream);
    nrm_kernel<<<NN / 4, 256, 0, stream>>>(f1, f2, scale, wts, f1q, f2q,
                                           diag, rse, cse, S1p, S2p, T1p, T2p);
    gemm_kernel<<<1024, 256, 0, stream>>>(f1q, f2q, rse, cse);
    fin_kernel<<<1, 1024, 0, stream>>>(rse, cse, diag, wts, S1p, S2p, T1p, T2p, out);
}